// Round 1
// baseline (349.371 us; speedup 1.0000x reference)
//
#include <hip/hip_runtime.h>
#include <hip/hip_bf16.h>
#include <cstdint>

// Problem dims (fixed): B=16, LQ=2048, EMB1=1024, EMB2=768, HDIM=1024, NHEAD=16, dh=64
//
// Algebra: out[b,l,h*64+d] = sigmoid(att[b,l,h]) * v[b,h*64+d]
//   att[b,l,h] = sum_e emb1[b,l,e] * Wqk[b,h,e] + attb[b,h]
//   Wqk[b,h,e] = sum_d k[b,h*64+d] * Wq[h*64+d, e]
//   attb[b,h]  = sum_d bq[h*64+d] * k[b,h*64+d]
//   k[b,:] = emb2[b,:] @ Wk^T + bk ;  v likewise.
//
// ws layout (bytes):
//   k    [16][1024] f32   @ 0       (65536)
//   v    [16][1024] f32   @ 65536   (65536)
//   attb [16][16]   f32   @ 131072  (1024)
//   wqk  [16][16][1024] bf16(ushort) @ 132096 (524288)   total 656384 B

__device__ __forceinline__ float bf_lo(uint32_t u) { return __uint_as_float(u << 16); }
__device__ __forceinline__ float bf_hi(uint32_t u) { return __uint_as_float(u & 0xFFFF0000u); }
__device__ __forceinline__ uint16_t f2bf(float f) {
    uint32_t u = __float_as_uint(f);
    u += 0x7FFFu + ((u >> 16) & 1u);   // RNE
    return (uint16_t)(u >> 16);
}

// ---------------- Kernel A: k, v = emb2 @ W^T + bias (fp32) ----------------
// grid (64, 2): x = h-tile of 16, y = kind (0=K, 1=V). 256 threads.
__global__ __launch_bounds__(256) void kv_kernel(
    const float* __restrict__ emb2, const float* __restrict__ Wk,
    const float* __restrict__ bk,   const float* __restrict__ Wv,
    const float* __restrict__ bv,   float* __restrict__ ws)
{
    const int kind  = blockIdx.y;
    const int htile = blockIdx.x;
    const float* W    = kind ? Wv : Wk;
    const float* bias = kind ? bv : bk;
    float* outp = ws + (kind ? 16384 : 0);

    __shared__ float se2[16 * 772];          // padded row stride 772 floats
    const int t = threadIdx.x;
    #pragma unroll 4
    for (int i = 0; i < 48; ++i) {
        int idx = i * 256 + t;               // 0..12287
        int b = idx / 768;
        int e = idx - b * 768;
        se2[b * 772 + e] = emb2[idx];
    }
    __syncthreads();

    const int hl = t >> 4, b = t & 15;       // 16 lanes share a W row (broadcast)
    const int h  = htile * 16 + hl;
    float acc = bias[h];
    const float4* W4 = (const float4*)(W + (size_t)h * 768);
    const float*  e2 = &se2[b * 772];
    #pragma unroll 4
    for (int j = 0; j < 192; ++j) {
        float4 w = W4[j];
        float4 a = *(const float4*)(e2 + j * 4);
        acc += w.x * a.x + w.y * a.y + w.z * a.z + w.w * a.w;
    }
    outp[b * 1024 + h] = acc;
}

// ---------------- Kernel B: fold Wqk (bf16) + att bias ----------------
// grid (16, 16): x = h, y = b. 256 threads; thread t owns cols {t, t+256, t+512, t+768}.
__global__ __launch_bounds__(256) void fold_kernel(
    const float* __restrict__ Wq, const float* __restrict__ bq,
    float* __restrict__ ws)
{
    const int h = blockIdx.x, b = blockIdx.y;
    const float* kvec = ws;                          // [16][1024]
    float* attb = ws + 32768;
    uint16_t* wqk = (uint16_t*)((char*)ws + 132096);

    __shared__ float kk[64];
    __shared__ float pb[64];
    const int t = threadIdx.x;
    if (t < 64) {
        float kv = kvec[b * 1024 + h * 64 + t];
        kk[t] = kv;
        pb[t] = kv * bq[h * 64 + t];
    }
    __syncthreads();
    if (t == 0) {
        float s = 0.f;
        #pragma unroll 8
        for (int d = 0; d < 64; ++d) s += pb[d];
        attb[b * 16 + h] = s;
    }

    float acc0 = 0.f, acc1 = 0.f, acc2 = 0.f, acc3 = 0.f;
    const float* Wbase = Wq + (size_t)(h * 64) * 1024 + t;
    #pragma unroll 4
    for (int d = 0; d < 64; ++d) {
        float s = kk[d];
        const float* Wr = Wbase + d * 1024;          // coalesced across threads
        acc0 += s * Wr[0];
        acc1 += s * Wr[256];
        acc2 += s * Wr[512];
        acc3 += s * Wr[768];
    }
    uint16_t* o = wqk + (size_t)(b * 16 + h) * 1024 + t;
    o[0]   = f2bf(acc0);
    o[256] = f2bf(acc1);
    o[512] = f2bf(acc2);
    o[768] = f2bf(acc3);
}

// ---------------- Kernel C: att + sigmoid gate + out (memory-bound stream) --
// grid (64, 16): x = 32-row block within batch, y = b. 256 threads = 4 waves.
// Wave w handles rows [blk*32 + w*8, +8). Lane (g = lane>>4, h = lane&15):
// partial att over e in [g*256, g*256+256) for head h; shfl_xor(16/32) reduce.
__global__ __launch_bounds__(256) void att_kernel(
    const float* __restrict__ emb1, const float* __restrict__ ws,
    float* __restrict__ out)
{
    const int blk = blockIdx.x;
    const int b   = blockIdx.y;
    const float* vvec = ws + 16384;
    const float* attb = ws + 32768;
    const uint16_t* wqk = (const uint16_t*)((const char*)ws + 132096);

    __shared__ uint16_t swqk[16 * 1032];     // row stride 1032 (pad 8 bf16, keeps b128 align)
    {
        const uint4* src = (const uint4*)(wqk + (size_t)b * 16384);
        const int t = threadIdx.x;
        #pragma unroll
        for (int i = 0; i < 8; ++i) {
            int c   = i * 256 + t;           // 0..2047 chunks of 8 bf16
            int row = c >> 7;
            int col = (c & 127) * 8;
            *(uint4*)&swqk[row * 1032 + col] = src[c];
        }
    }
    __syncthreads();

    const int w    = threadIdx.x >> 6;
    const int lane = threadIdx.x & 63;
    const int g = lane >> 4, h = lane & 15;

    float vloc[16];
    {
        const float4* vp = (const float4*)(vvec + b * 1024 + lane * 16);
        #pragma unroll
        for (int j = 0; j < 4; ++j) {
            float4 q = vp[j];
            vloc[j*4+0] = q.x; vloc[j*4+1] = q.y; vloc[j*4+2] = q.z; vloc[j*4+3] = q.w;
        }
    }
    const float attb_l = attb[b * 16 + h];

    const int row0 = blk * 32 + w * 8;
    const float* A  = emb1 + ((size_t)b * 2048 + row0) * 1024;
    const float* Ag = A + g * 256;
    const uint16_t* wrow = &swqk[h * 1032 + g * 256];

    float acc[8];
    #pragma unroll
    for (int r = 0; r < 8; ++r) acc[r] = 0.f;

    for (int c = 0; c < 32; ++c) {
        uint4 wp = *(const uint4*)(wrow + c * 8);
        float wq0 = bf_lo(wp.x), wq1 = bf_hi(wp.x);
        float wq2 = bf_lo(wp.y), wq3 = bf_hi(wp.y);
        float wq4 = bf_lo(wp.z), wq5 = bf_hi(wp.z);
        float wq6 = bf_lo(wp.w), wq7 = bf_hi(wp.w);
        #pragma unroll
        for (int r = 0; r < 8; ++r) {
            const float4* ap = (const float4*)(Ag + r * 1024 + c * 8);
            float4 a0 = ap[0], a1 = ap[1];
            acc[r] += wq0*a0.x + wq1*a0.y + wq2*a0.z + wq3*a0.w
                    + wq4*a1.x + wq5*a1.y + wq6*a1.z + wq7*a1.w;
        }
    }

    float sig[8];
    #pragma unroll
    for (int r = 0; r < 8; ++r) {
        float t2 = acc[r];
        t2 += __shfl_xor(t2, 16);
        t2 += __shfl_xor(t2, 32);
        t2 += attb_l;
        sig[r] = 1.0f / (1.0f + __expf(-t2));
    }

    float* orow = out + ((size_t)b * 2048 + row0) * 1024 + lane * 16;
    #pragma unroll
    for (int r = 0; r < 8; ++r) {
        float a = __shfl(sig[r], lane >> 2);     // lane L needs head L/4; src lane has that h
        float4 o0, o1, o2, o3;
        o0.x = a*vloc[0];  o0.y = a*vloc[1];  o0.z = a*vloc[2];  o0.w = a*vloc[3];
        o1.x = a*vloc[4];  o1.y = a*vloc[5];  o1.z = a*vloc[6];  o1.w = a*vloc[7];
        o2.x = a*vloc[8];  o2.y = a*vloc[9];  o2.z = a*vloc[10]; o2.w = a*vloc[11];
        o3.x = a*vloc[12]; o3.y = a*vloc[13]; o3.z = a*vloc[14]; o3.w = a*vloc[15];
        float4* op = (float4*)(orow + (size_t)r * 1024);
        op[0] = o0; op[1] = o1; op[2] = o2; op[3] = o3;
    }
}

extern "C" void kernel_launch(void* const* d_in, const int* in_sizes, int n_in,
                              void* d_out, int out_size, void* d_ws, size_t ws_size,
                              hipStream_t stream) {
    const float* emb1 = (const float*)d_in[0];
    const float* emb2 = (const float*)d_in[1];
    const float* Wq   = (const float*)d_in[2];
    const float* bq   = (const float*)d_in[3];
    const float* Wk   = (const float*)d_in[4];
    const float* bk   = (const float*)d_in[5];
    const float* Wv   = (const float*)d_in[6];
    const float* bv   = (const float*)d_in[7];
    float* out = (float*)d_out;
    float* ws  = (float*)d_ws;

    kv_kernel<<<dim3(64, 2), 256, 0, stream>>>(emb2, Wk, bk, Wv, bv, ws);
    fold_kernel<<<dim3(16, 16), 256, 0, stream>>>(Wq, bq, ws);
    att_kernel<<<dim3(64, 16), 256, 0, stream>>>(emb1, ws, out);
}

// Round 2
// 304.262 us; speedup vs baseline: 1.1483x; 1.1483x over previous
//
#include <hip/hip_runtime.h>
#include <hip/hip_fp16.h>
#include <cstdint>

// Dims fixed: B=16, LQ=2048, EMB1=1024, EMB2=768, HDIM=1024, NHEAD=16, dh=64
//
// Algebra: out[b,l,h*64+d] = sigmoid(att[b,l,h]) * v[b,h*64+d]
//   att[b,l,h] = sum_e emb1[b,l,e] * Wqk[b,h,e] + attb[b,h]
//   Wqk[b,h,e] = sum_d k[b,h*64+d] * Wq[h*64+d, e]     (stored fp16)
//   attb[b,h]  = sum_d bq[h*64+d] * k[b,h*64+d]
//   k[b,:] = emb2[b,:] @ Wk^T + bk ;  v likewise.
//
// ws layout (bytes):
//   k    [16][1024] f32  @ 0       (65536)
//   v    [16][1024] f32  @ 65536   (65536)
//   attb [16][16]   f32  @ 131072  (1024)
//   wqk  [16][16][1024] fp16 @ 132096 (524288)   total 656384 B

// ---------------- Kernel A: k, v = emb2 @ W^T + bias (fp32) ----------------
// grid (64, 2): x = h-tile of 16, y = kind (0=K, 1=V). 256 threads.
__global__ __launch_bounds__(256) void kv_kernel(
    const float* __restrict__ emb2, const float* __restrict__ Wk,
    const float* __restrict__ bk,   const float* __restrict__ Wv,
    const float* __restrict__ bv,   float* __restrict__ ws)
{
    const int kind  = blockIdx.y;
    const int htile = blockIdx.x;
    const float* W    = kind ? Wv : Wk;
    const float* bias = kind ? bv : bk;
    float* outp = ws + (kind ? 16384 : 0);

    __shared__ float se2[16 * 772];          // padded row stride 772 floats
    const int t = threadIdx.x;
    #pragma unroll 4
    for (int i = 0; i < 48; ++i) {
        int idx = i * 256 + t;               // 0..12287
        int b = idx / 768;
        int e = idx - b * 768;
        se2[b * 772 + e] = emb2[idx];
    }
    __syncthreads();

    const int hl = t >> 4, b = t & 15;       // 16 lanes share a W row (broadcast)
    const int h  = htile * 16 + hl;
    float acc = bias[h];
    const float4* W4 = (const float4*)(W + (size_t)h * 768);
    const float*  e2 = &se2[b * 772];
    #pragma unroll 4
    for (int j = 0; j < 192; ++j) {
        float4 w = W4[j];
        float4 a = *(const float4*)(e2 + j * 4);
        acc += w.x * a.x + w.y * a.y + w.z * a.z + w.w * a.w;
    }
    outp[b * 1024 + h] = acc;
}

// ---------------- Kernel B: fold Wqk (fp16) + att bias ----------------
// grid (16, 4): x = h, y = e-tile of 256. Reads Wq ONCE (4 MB total).
// Thread t owns column e = et*256 + t; accumulates all 16 batches.
__global__ __launch_bounds__(256) void fold_kernel(
    const float* __restrict__ Wq, const float* __restrict__ bq,
    float* __restrict__ ws)
{
    const int h  = blockIdx.x;
    const int et = blockIdx.y;
    const float* kvec = ws;                           // [16][1024]
    float* attb = ws + 32768;
    __half* wqk = (__half*)((char*)ws + 132096);

    __shared__ float kk[16 * 64];                     // kk[b][d]
    const int t = threadIdx.x;
    {
        int idx0 = t;                                  // 1024 floats / 256 = 4 each
        #pragma unroll
        for (int i = 0; i < 4; ++i) {
            int idx = i * 256 + idx0;
            int b = idx >> 6, d = idx & 63;
            kk[b * 64 + d] = kvec[b * 1024 + h * 64 + d];
        }
    }
    __syncthreads();

    if (et == 0 && t < 16) {                           // attb[b][h]
        float s = 0.f;
        #pragma unroll 8
        for (int d = 0; d < 64; ++d) s += kk[t * 64 + d] * bq[h * 64 + d];
        attb[t * 16 + h] = s;
    }

    const int e = et * 256 + t;
    float acc[16];
    #pragma unroll
    for (int b = 0; b < 16; ++b) acc[b] = 0.f;

    const float* Wcol = Wq + (size_t)(h * 64) * 1024 + e;
    for (int d = 0; d < 64; ++d) {
        float wv = Wcol[(size_t)d * 1024];             // coalesced across t
        #pragma unroll
        for (int b = 0; b < 16; ++b) acc[b] += kk[b * 64 + d] * wv;
    }
    #pragma unroll
    for (int b = 0; b < 16; ++b)
        wqk[(size_t)(b * 16 + h) * 1024 + e] = __float2half_rn(acc[b]);
}

// ---------------- Kernel C: att + sigmoid gate + out (streaming) ----------
// grid (64, 16): x = 32-row block, y = batch. 256 threads = 4 waves, 8 rows/wave.
// Lane covers e = seg*256 + lane*4 + j (fully coalesced 1KB loads/stores).
// w staged in LDS fp16, swizzled: sw[(h*64+lane)*16 + seg*4 + j] so each lane's
// 16 weights for head h are 32B contiguous (2x ds_read_b128).
// Head-splitting butterfly: lane ends owning head bitrev4(lane&15).
__global__ __launch_bounds__(256) void att_kernel(
    const float* __restrict__ emb1, const float* __restrict__ ws,
    float* __restrict__ out)
{
    const int bx = blockIdx.x;
    const int b  = blockIdx.y;
    const float*  vvec = ws + 16384 + b * 1024;
    const float*  attb = ws + 32768 + b * 16;
    const __half* wqk  = (const __half*)((const char*)ws + 132096) + (size_t)b * 16384;

    __shared__ __half sw[16 * 64 * 16];               // 32768 B

    const int t = threadIdx.x;
    #pragma unroll
    for (int i = 0; i < 8; ++i) {
        int c   = i * 256 + t;                        // 2048 chunks of 8 halves
        int h   = c >> 7;
        int seg = (c >> 5) & 3;
        int lp  = c & 31;                             // lane pair
        uint4 vld = *(const uint4*)(wqk + h * 1024 + seg * 256 + lp * 8);
        *(uint2*)&sw[(h * 64 + lp * 2    ) * 16 + seg * 4] = make_uint2(vld.x, vld.y);
        *(uint2*)&sw[(h * 64 + lp * 2 + 1) * 16 + seg * 4] = make_uint2(vld.z, vld.w);
    }
    __syncthreads();

    const int w    = t >> 6;
    const int lane = t & 63;
    const int g    = lane >> 4;

    // v at this lane's write positions
    float4 vv[4];
    #pragma unroll
    for (int s = 0; s < 4; ++s) vv[s] = *(const float4*)(vvec + s * 256 + lane * 4);

    const int l0 = lane & 1, l1 = (lane >> 1) & 1, l2 = (lane >> 2) & 1, l3 = (lane >> 3) & 1;
    const int hmine = (l0 << 3) | (l1 << 2) | (l2 << 1) | l3;   // bitrev4(lane&15)
    const float attb_l = attb[hmine];

    int src[4];
    #pragma unroll
    for (int s = 0; s < 4; ++s)
        src[s] = ((g & 1) << 3) | ((g >> 1) << 2) | ((s & 1) << 1) | (s >> 1);

    const int row0 = bx * 32 + w * 8;
    const float* Abase = emb1 + ((size_t)b * 2048 + row0) * 1024 + lane * 4;
    float*       Obase = out  + ((size_t)b * 2048 + row0) * 1024 + lane * 4;
    const __half2* wl2 = (const __half2*)(sw + lane * 16);      // + h*512 half2's

    for (int r = 0; r < 8; ++r) {
        const float* A = Abase + r * 1024;
        float4 a0 = *(const float4*)(A);
        float4 a1 = *(const float4*)(A + 256);
        float4 a2 = *(const float4*)(A + 512);
        float4 a3 = *(const float4*)(A + 768);

        float acc[16];
        #pragma unroll
        for (int h = 0; h < 16; ++h) {
            const __half2* wp = wl2 + h * 512;        // (h*64+lane)*16 halves
            float2 f0 = __half22float2(wp[0]);
            float2 f1 = __half22float2(wp[1]);
            float2 f2 = __half22float2(wp[2]);
            float2 f3 = __half22float2(wp[3]);
            float2 f4 = __half22float2(wp[4]);
            float2 f5 = __half22float2(wp[5]);
            float2 f6 = __half22float2(wp[6]);
            float2 f7 = __half22float2(wp[7]);
            float s;
            s  = f0.x * a0.x + f0.y * a0.y + f1.x * a0.z + f1.y * a0.w;
            s += f2.x * a1.x + f2.y * a1.y + f3.x * a1.z + f3.y * a1.w;
            s += f4.x * a2.x + f4.y * a2.y + f5.x * a2.z + f5.y * a2.w;
            s += f6.x * a3.x + f6.y * a3.y + f7.x * a3.z + f7.y * a3.w;
            acc[h] = s;
        }

        // head-splitting butterfly: 17 shuffles total
        {   // m=1: keep 8 heads by lane bit0
            const bool hi = l0;
            #pragma unroll
            for (int i = 0; i < 8; ++i) {
                float send = hi ? acc[i] : acc[i + 8];
                float keep = hi ? acc[i + 8] : acc[i];
                acc[i] = keep + __shfl_xor(send, 1);
            }
        }
        {   // m=2
            const bool hi = l1;
            #pragma unroll
            for (int i = 0; i < 4; ++i) {
                float send = hi ? acc[i] : acc[i + 4];
                float keep = hi ? acc[i + 4] : acc[i];
                acc[i] = keep + __shfl_xor(send, 2);
            }
        }
        {   // m=4
            const bool hi = l2;
            #pragma unroll
            for (int i = 0; i < 2; ++i) {
                float send = hi ? acc[i] : acc[i + 2];
                float keep = hi ? acc[i + 2] : acc[i];
                acc[i] = keep + __shfl_xor(send, 4);
            }
        }
        {   // m=8
            const bool hi = l3;
            float send = hi ? acc[0] : acc[1];
            float keep = hi ? acc[1] : acc[0];
            acc[0] = keep + __shfl_xor(send, 8);
        }
        float r0 = acc[0];
        r0 += __shfl_xor(r0, 16);
        r0 += __shfl_xor(r0, 32);

        float att  = r0 + attb_l;
        float gate = 1.0f / (1.0f + __expf(-att));

        float* O = Obase + (size_t)r * 1024;
        #pragma unroll
        for (int s = 0; s < 4; ++s) {
            float gs = __shfl(gate, src[s]);
            float4 o;
            o.x = gs * vv[s].x; o.y = gs * vv[s].y;
            o.z = gs * vv[s].z; o.w = gs * vv[s].w;
            *(float4*)(O + s * 256) = o;
        }
    }
}

extern "C" void kernel_launch(void* const* d_in, const int* in_sizes, int n_in,
                              void* d_out, int out_size, void* d_ws, size_t ws_size,
                              hipStream_t stream) {
    const float* emb1 = (const float*)d_in[0];
    const float* emb2 = (const float*)d_in[1];
    const float* Wq   = (const float*)d_in[2];
    const float* bq   = (const float*)d_in[3];
    const float* Wk   = (const float*)d_in[4];
    const float* bk   = (const float*)d_in[5];
    const float* Wv   = (const float*)d_in[6];
    const float* bv   = (const float*)d_in[7];
    float* out = (float*)d_out;
    float* ws  = (float*)d_ws;

    kv_kernel  <<<dim3(64, 2),  256, 0, stream>>>(emb2, Wk, bk, Wv, bv, ws);
    fold_kernel<<<dim3(16, 4),  256, 0, stream>>>(Wq, bq, ws);
    att_kernel <<<dim3(64, 16), 256, 0, stream>>>(emb1, ws, out);
}